// Round 2
// baseline (2133.530 us; speedup 1.0000x reference)
//
#include <hip/hip_runtime.h>
#include <cstdint>
#include <cstddef>

typedef __bf16 bf16;
typedef __bf16 bf16x8 __attribute__((ext_vector_type(8)));
typedef __bf16 bf16x4v __attribute__((ext_vector_type(4)));
typedef float f32x4 __attribute__((ext_vector_type(4)));
typedef unsigned int u32x4 __attribute__((ext_vector_type(4)));

static constexpr int NB = 8, NH = 16, F = 1024, FH = 64, NTOK = 577, NPAD = 640;
static constexpr int NLAYER = 6, HID = 4096, NRD = 2212;
static constexpr int MROWS = NB * NPAD; // 5120

// ---- workspace layout (bytes) ----
static constexpr size_t H_OFF    = 0;                                   // [5120][1024] bf16
static constexpr size_t Q_OFF    = H_OFF    + (size_t)MROWS*F*2;        // [8][16][640][64] bf16
static constexpr size_t K_OFF    = Q_OFF    + (size_t)NB*NH*NPAD*FH*2;
static constexpr size_t V_OFF    = K_OFF    + (size_t)NB*NH*NPAD*FH*2;  // [8][16][64][640] bf16 (transposed)
static constexpr size_t O_OFF    = V_OFF    + (size_t)NB*NH*FH*NPAD*2;  // [5120][1024] bf16
static constexpr size_t BIAS_OFF = O_OFF    + (size_t)MROWS*F*2;        // [16][640][640] f32
static constexpr size_t M1_OFF   = BIAS_OFF + (size_t)NH*NPAD*NPAD*4;   // [5120][4096] bf16
static constexpr size_t WQKV_OFF = M1_OFF   + (size_t)MROWS*HID*2;
static constexpr size_t WPROJ_OFF= WQKV_OFF + (size_t)3*F*F*2;
static constexpr size_t WM1_OFF  = WPROJ_OFF+ (size_t)F*F*2;
static constexpr size_t WM2_OFF  = WM1_OFF  + (size_t)HID*F*2;
static constexpr size_t WS_NEED  = WM2_OFF  + (size_t)HID*F*2;

__device__ __forceinline__ f32x4 mfma16(bf16x8 a, bf16x8 b, f32x4 c) {
  return __builtin_amdgcn_mfma_f32_16x16x32_bf16(a, b, c, 0, 0, 0);
}

// async global(16B per lane) -> LDS (wave-uniform base + lane*16)
__device__ __forceinline__ void gload16(const bf16* g, bf16* l) {
  __builtin_amdgcn_global_load_lds(
      (const __attribute__((address_space(1))) void*)g,
      (__attribute__((address_space(3))) void*)l, 16, 0, 0);
}

// ---------------- elementwise helpers ----------------
__global__ __launch_bounds__(256) void copy_kernel(const float* __restrict__ s, float* __restrict__ d) {
  size_t i = ((size_t)blockIdx.x*256 + threadIdx.x)*4;
  *(float4*)(d + i) = *(const float4*)(s + i);
}

// fused fp32->bf16 convert of the 4 weight matrices of one layer
static constexpr int CVT_N0 = 3*F*F;           // 3145728
static constexpr int CVT_N1 = CVT_N0 + F*F;    // 4194304
static constexpr int CVT_N2 = CVT_N1 + HID*F;  // 8388608
static constexpr int CVT_N3 = CVT_N2 + F*HID;  // 12582912
__global__ __launch_bounds__(256) void cvt4_kernel(
    const float* __restrict__ s0, const float* __restrict__ s1,
    const float* __restrict__ s2, const float* __restrict__ s3,
    bf16* __restrict__ d0, bf16* __restrict__ d1,
    bf16* __restrict__ d2, bf16* __restrict__ d3) {
  int i = (blockIdx.x*256 + threadIdx.x)*4;
  const float* s; bf16* d; int off;
  if (i < CVT_N0)      { s = s0; d = d0; off = i; }
  else if (i < CVT_N1) { s = s1; d = d1; off = i - CVT_N0; }
  else if (i < CVT_N2) { s = s2; d = d2; off = i - CVT_N1; }
  else                 { s = s3; d = d3; off = i - CVT_N2; }
  float4 v = *(const float4*)(s + off);
  bf16x4v o;
  o[0] = (bf16)v.x; o[1] = (bf16)v.y; o[2] = (bf16)v.z; o[3] = (bf16)v.w;
  *(bf16x4v*)(d + off) = o;
}

// LayerNorm: X (fp32, [B,577,1024]) -> H (bf16, padded rows [B,640,1024])
__global__ __launch_bounds__(256) void ln_kernel(const float* __restrict__ X,
    const float* __restrict__ g, const float* __restrict__ bta, bf16* __restrict__ H) {
  int row = blockIdx.x;                 // 0..4615  (b*577+tok)
  int bb = row / NTOK, tok = row % NTOK;
  const float* x = X + (size_t)row * F;
  int tid = threadIdx.x;
  float4 v = *(const float4*)(x + tid*4);
  float s  = v.x + v.y + v.z + v.w;
  float s2 = v.x*v.x + v.y*v.y + v.z*v.z + v.w*v.w;
  #pragma unroll
  for (int off = 1; off < 64; off <<= 1) {
    s  += __shfl_xor(s,  off, 64);
    s2 += __shfl_xor(s2, off, 64);
  }
  __shared__ float red[8];
  int w = tid >> 6;
  if ((tid & 63) == 0) { red[w] = s; red[4+w] = s2; }
  __syncthreads();
  s  = red[0]+red[1]+red[2]+red[3];
  s2 = red[4]+red[5]+red[6]+red[7];
  float mean = s * (1.0f/1024.0f);
  float var  = s2 * (1.0f/1024.0f) - mean*mean;
  float rstd = rsqrtf(fmaxf(var, 0.0f) + 1e-6f);
  float4 gg  = *(const float4*)(g + tid*4);
  float4 bb4 = *(const float4*)(bta + tid*4);
  bf16x4v o;
  o[0] = (bf16)((v.x-mean)*rstd*gg.x + bb4.x);
  o[1] = (bf16)((v.y-mean)*rstd*gg.y + bb4.y);
  o[2] = (bf16)((v.z-mean)*rstd*gg.z + bb4.z);
  o[3] = (bf16)((v.w-mean)*rstd*gg.w + bb4.w);
  *(bf16x4v*)(H + ((size_t)bb*NPAD + tok)*F + tid*4) = o;
}

// Relative-position bias plane: [16][640][640] fp32; pads = -1e30 (doubles as col mask)
__global__ __launch_bounds__(256) void bias_kernel(const float* __restrict__ table, float* __restrict__ bias) {
  int bi = blockIdx.x;           // 16*640
  int h = bi / NPAD, n = bi % NPAD;
  float* out = bias + ((size_t)h*NPAD + n)*NPAD;
  for (int m = threadIdx.x; m < NPAD; m += 256) {
    float val;
    if (n >= NTOK || m >= NTOK) val = -1e30f;
    else {
      int idx;
      if (n == 0 && m == 0) idx = NRD - 1;
      else if (m == 0)      idx = NRD - 2;
      else if (n == 0)      idx = NRD - 3;
      else {
        int pn = n - 1, pm = m - 1;
        int rn = pn / 24, cn = pn % 24, rm = pm / 24, cm = pm % 24;
        idx = (rn - rm + 23)*47 + (cn - cm + 23);
      }
      val = table[idx*NH + h];
    }
    out[m] = val;
  }
}

// ---------------- GEMM: C[m,n] = A[m,:] . Bw[n,:]  (both K-contiguous bf16) ----------------
// BMT: 1 -> BM=64 (grid-fill for small N), 2 -> BM=128.  BN=128, BK=32, 256 threads.
// Staging: global_load_lds dwordx4, linear LDS [BM|128][32] (m97 structure).
// EPI 0: qkv split->Q,K,Vt
// EPI 1: split-K over blockIdx.z; x atomicAdd= p1[n]*(acc + (z==0? p0[n]:0))  (fp32)
// EPI 2: gelu->bf16 bout
template<int BMT, int EPI>
__global__ __launch_bounds__(256, 2)
void gemm_kernel(const bf16* __restrict__ A, const bf16* __restrict__ Bw, int K, int ldc,
                 const float* __restrict__ p0, const float* __restrict__ p1,
                 float* __restrict__ xout, bf16* __restrict__ bout,
                 bf16* __restrict__ q_out, bf16* __restrict__ k_out, bf16* __restrict__ v_out)
{
  constexpr int BM = 64*BMT;
  constexpr int WN = (BMT==2) ? 2 : 4;      // waves along N
  constexpr int NF = 128/(WN*16);           // B frags per wave: 4 (BMT=2) or 2 (BMT=1)
  __shared__ bf16 As[BM*32], Bs[128*32];
  const int tid = threadIdx.x;
  const int lane = tid & 63, w = tid >> 6;
  const int wm = (BMT==2) ? (w>>1) : 0;
  const int wn = (BMT==2) ? (w&1) : w;
  const int lg = lane >> 4, lr = lane & 15;
  const int m0 = blockIdx.x * BM, n0 = blockIdx.y * 128;

  const f32x4 fz = {0.f, 0.f, 0.f, 0.f};
  f32x4 acc[4][NF];
  #pragma unroll
  for (int i = 0; i < 4; ++i)
    #pragma unroll
    for (int j = 0; j < NF; ++j) acc[i][j] = fz;

  // per-lane global source within a 16-row (1024B) load granule
  const int srow = lane >> 2;        // 0..15
  const int scol = (lane & 3) * 8;   // bf16 col

  // split-K: blockIdx.z owns K-range [kbeg, kbeg+klen). gridDim.z==1 for EPI 0/2.
  const int klen = K / (int)gridDim.z;
  const int kbeg = (int)blockIdx.z * klen;

  for (int kt = kbeg; kt < kbeg + klen; kt += 32) {
    if (BMT == 2) {
      #pragma unroll
      for (int j = 0; j < 2; ++j) {
        int li = w + j*4;
        gload16(A + (size_t)(m0 + li*16 + srow)*K + kt + scol, &As[li*512]);
      }
    } else {
      gload16(A + (size_t)(m0 + w*16 + srow)*K + kt + scol, &As[w*512]);
    }
    #pragma unroll
    for (int j = 0; j < 2; ++j) {
      int li = w*2 + j;
      gload16(Bw + (size_t)(n0 + li*16 + srow)*K + kt + scol, &Bs[li*512]);
    }
    __syncthreads();                 // drains vmcnt before barrier (loads landed)
    bf16x8 af[4], bfv[NF];
    #pragma unroll
    for (int f = 0; f < 4; ++f)
      af[f]  = *(const bf16x8*)&As[(wm*64 + f*16 + lr)*32 + lg*8];
    #pragma unroll
    for (int f = 0; f < NF; ++f)
      bfv[f] = *(const bf16x8*)&Bs[(wn*(NF*16) + f*16 + lr)*32 + lg*8];
    #pragma unroll
    for (int mf = 0; mf < 4; ++mf)
      #pragma unroll
      for (int nf = 0; nf < NF; ++nf)
        acc[mf][nf] = mfma16(af[mf], bfv[nf], acc[mf][nf]);
    __syncthreads();                 // reads done before next overwrite
  }

  #pragma unroll
  for (int mf = 0; mf < 4; ++mf) {
    const int row = m0 + wm*64 + mf*16 + lg*4;       // + r (4-row group never crosses 640)
    const int bidx = row / NPAD;
    const int tokbase = row - bidx*NPAD;
    #pragma unroll
    for (int nf = 0; nf < NF; ++nf) {
      const int col = n0 + wn*(NF*16) + nf*16 + lr;
      if (EPI == 0) {
        const int sec = col >> 10, ci = col & 1023;
        const int hh = ci >> 6, fh = ci & 63;
        const size_t bhh = (size_t)bidx*NH + hh;
        #pragma unroll
        for (int r = 0; r < 4; ++r) {
          float v = acc[mf][nf][r];
          if (sec == 0)      q_out[(bhh*NPAD + tokbase + r)*FH + fh] = (bf16)((v + p0[ci]) * 0.125f);
          else if (sec == 1) k_out[(bhh*NPAD + tokbase + r)*FH + fh] = (bf16)v;
          else               v_out[(bhh*FH + fh)*NPAD + tokbase + r] = (bf16)(v + p1[ci]);
        }
      } else if (EPI == 1) {
        const float pb = (blockIdx.z == 0) ? p0[col] : 0.0f;
        const float sc = p1[col];
        #pragma unroll
        for (int r = 0; r < 4; ++r) {
          int tok = tokbase + r;
          if (tok < NTOK) {
            size_t idx = ((size_t)bidx*NTOK + tok)*F + col;
            atomicAdd(xout + idx, sc * (acc[mf][nf][r] + pb));
          }
        }
      } else {
        const float pb = p0[col];
        #pragma unroll
        for (int r = 0; r < 4; ++r) {
          float t = acc[mf][nf][r] + pb;
          float gl = 0.5f*t*(1.0f + erff(t*0.70710678118f));
          bout[(size_t)(row + r)*ldc + col] = (bf16)gl;
        }
      }
    }
  }
}

// ---------------- flash attention: Q[B,H,640,64], K[B,H,640,64], Vt[B,H,64,640] -> O[5120][1024] bf16
__global__ __launch_bounds__(256, 2) void attn_kernel(
    const bf16* __restrict__ Qb, const bf16* __restrict__ Kb,
    const bf16* __restrict__ Vt, const float* __restrict__ Bias,
    bf16* __restrict__ O)
{
  __shared__ bf16 Qt[64*72], Kt[64*72], Vs[64*72], Pt[4][16*72];
  const int bh = blockIdx.x, rb = blockIdx.y;
  const int b = bh >> 4, h = bh & 15;
  const int tid = threadIdx.x, lane = tid & 63, w = tid >> 6;
  const int lg = lane >> 4, lr = lane & 15;

  const bf16*  Qg = Qb + ((size_t)bh*NPAD + rb*64)*FH;
  const bf16*  Kg = Kb + (size_t)bh*NPAD*FH;
  const bf16*  Vg = Vt + (size_t)bh*FH*NPAD;
  const float* Bg = Bias + (size_t)h*NPAD*NPAD;

  #pragma unroll
  for (int i = 0; i < 2; ++i) {
    int gidx = tid + i*256, r = gidx >> 3, cg = gidx & 7;
    *(u32x4*)&Qt[r*72 + cg*8] = *(const u32x4*)&Qg[r*64 + cg*8];
  }
  __syncthreads();
  bf16x8 qf0 = *(const bf16x8*)&Qt[(w*16+lr)*72 + lg*8];
  bf16x8 qf1 = *(const bf16x8*)&Qt[(w*16+lr)*72 + 32 + lg*8];

  const f32x4 fz = {0.f, 0.f, 0.f, 0.f};
  float m_run[4], l_run[4];
  f32x4 o_acc[4];
  #pragma unroll
  for (int r = 0; r < 4; ++r) { m_run[r] = -3.0e38f; l_run[r] = 0.0f; }
  #pragma unroll
  for (int f = 0; f < 4; ++f) o_acc[f] = fz;

  const int qrow = rb*64 + w*16 + lg*4;

  for (int cb = 0; cb < 10; ++cb) {
    __syncthreads();
    #pragma unroll
    for (int i = 0; i < 2; ++i) {
      int gidx = tid + i*256, r = gidx >> 3, cg = gidx & 7;
      *(u32x4*)&Kt[r*72 + cg*8] = *(const u32x4*)&Kg[(size_t)(cb*64+r)*64 + cg*8];
      *(u32x4*)&Vs[r*72 + cg*8] = *(const u32x4*)&Vg[(size_t)r*NPAD + cb*64 + cg*8];
    }
    __syncthreads();

    f32x4 s[4];
    #pragma unroll
    for (int nf = 0; nf < 4; ++nf) {
      bf16x8 k0 = *(const bf16x8*)&Kt[(nf*16+lr)*72 + lg*8];
      bf16x8 k1 = *(const bf16x8*)&Kt[(nf*16+lr)*72 + 32 + lg*8];
      s[nf] = mfma16(qf1, k1, mfma16(qf0, k0, fz));
    }
    #pragma unroll
    for (int nf = 0; nf < 4; ++nf)
      #pragma unroll
      for (int r = 0; r < 4; ++r)
        s[nf][r] += Bg[(size_t)(qrow + r)*NPAD + cb*64 + nf*16 + lr];

    float pm[4], sc[4], rs[4];
    #pragma unroll
    for (int r = 0; r < 4; ++r)
      pm[r] = fmaxf(fmaxf(s[0][r], s[1][r]), fmaxf(s[2][r], s[3][r]));
    #pragma unroll
    for (int off = 1; off < 16; off <<= 1)
      #pragma unroll
      for (int r = 0; r < 4; ++r)
        pm[r] = fmaxf(pm[r], __shfl_xor(pm[r], off, 64));
    #pragma unroll
    for (int r = 0; r < 4; ++r) {
      float mn = fmaxf(m_run[r], pm[r]);
      sc[r] = __expf(m_run[r] - mn);
      m_run[r] = mn;
      rs[r] = 0.0f;
    }
    #pragma unroll
    for (int nf = 0; nf < 4; ++nf)
      #pragma unroll
      for (int r = 0; r < 4; ++r) {
        float p = __expf(s[nf][r] - m_run[r]);
        s[nf][r] = p;
        rs[r] += p;
      }
    #pragma unroll
    for (int off = 1; off < 16; off <<= 1)
      #pragma unroll
      for (int r = 0; r < 4; ++r)
        rs[r] += __shfl_xor(rs[r], off, 64);
    #pragma unroll
    for (int r = 0; r < 4; ++r) l_run[r] = l_run[r]*sc[r] + rs[r];
    #pragma unroll
    for (int f = 0; f < 4; ++f) {
      o_acc[f][0] *= sc[0]; o_acc[f][1] *= sc[1];
      o_acc[f][2] *= sc[2]; o_acc[f][3] *= sc[3];
    }
    bf16* Ptw = &Pt[w][0];
    #pragma unroll
    for (int nf = 0; nf < 4; ++nf)
      #pragma unroll
      for (int r = 0; r < 4; ++r)
        Ptw[(lg*4 + r)*72 + nf*16 + lr] = (bf16)s[nf][r];
    __syncthreads();
    #pragma unroll
    for (int kc = 0; kc < 2; ++kc) {
      bf16x8 pa = *(const bf16x8*)&Ptw[lr*72 + kc*32 + lg*8];
      #pragma unroll
      for (int f = 0; f < 4; ++f) {
        bf16x8 vf = *(const bf16x8*)&Vs[(f*16+lr)*72 + kc*32 + lg*8];
        o_acc[f] = mfma16(pa, vf, o_acc[f]);
      }
    }
  }

  const int tokr = rb*64 + w*16 + lg*4;
  #pragma unroll
  for (int f = 0; f < 4; ++f)
    #pragma unroll
    for (int r = 0; r < 4; ++r) {
      float ov = o_acc[f][r] / l_run[r];
      O[((size_t)b*NPAD + tokr + r)*F + h*64 + f*16 + lr] = (bf16)ov;
    }
}

extern "C" void kernel_launch(void* const* d_in, const int* in_sizes, int n_in,
                              void* d_out, int out_size, void* d_ws, size_t ws_size,
                              hipStream_t stream) {
  (void)in_sizes; (void)n_in; (void)out_size;
  if (ws_size < WS_NEED) return;

  const float* tokens     = (const float*)d_in[0];
  const float* ln1_g      = (const float*)d_in[1];
  const float* ln1_b      = (const float*)d_in[2];
  const float* q_bias     = (const float*)d_in[3];
  const float* v_bias     = (const float*)d_in[4];
  const float* qkv_w      = (const float*)d_in[5];
  const float* relpos     = (const float*)d_in[6];
  const float* proj_w     = (const float*)d_in[7];
  const float* proj_b     = (const float*)d_in[8];
  const float* scale_attn = (const float*)d_in[9];
  const float* ln2_g      = (const float*)d_in[10];
  const float* ln2_b      = (const float*)d_in[11];
  const float* mlp_w1     = (const float*)d_in[12];
  const float* mlp_b1     = (const float*)d_in[13];
  const float* mlp_w2     = (const float*)d_in[14];
  const float* mlp_b2     = (const float*)d_in[15];
  const float* scale_mlp  = (const float*)d_in[16];

  char* ws = (char*)d_ws;
  bf16*  H     = (bf16*)(ws + H_OFF);
  bf16*  Qb    = (bf16*)(ws + Q_OFF);
  bf16*  Kb    = (bf16*)(ws + K_OFF);
  bf16*  Vt    = (bf16*)(ws + V_OFF);
  bf16*  Ob    = (bf16*)(ws + O_OFF);
  float* Bias  = (float*)(ws + BIAS_OFF);
  bf16*  M1    = (bf16*)(ws + M1_OFF);
  bf16*  Wqkv  = (bf16*)(ws + WQKV_OFF);
  bf16*  Wproj = (bf16*)(ws + WPROJ_OFF);
  bf16*  Wm1   = (bf16*)(ws + WM1_OFF);
  bf16*  Wm2   = (bf16*)(ws + WM2_OFF);
  float* X     = (float*)d_out;

  copy_kernel<<<NB*NTOK, 256, 0, stream>>>(tokens, X);   // x = tokens (fp32 residual stream)

  for (int i = 0; i < NLAYER; ++i) {
    cvt4_kernel<<<CVT_N3/(256*4), 256, 0, stream>>>(
        qkv_w + (size_t)i*3*F*F, proj_w + (size_t)i*F*F,
        mlp_w1 + (size_t)i*HID*F, mlp_w2 + (size_t)i*F*HID,
        Wqkv, Wproj, Wm1, Wm2);
    bias_kernel<<<NH*NPAD, 256, 0, stream>>>(relpos + (size_t)i*NRD*NH, Bias);

    ln_kernel<<<NB*NTOK, 256, 0, stream>>>(X, ln1_g + i*F, ln1_b + i*F, H);
    gemm_kernel<2,0><<<dim3(MROWS/128, 3*F/128), 256, 0, stream>>>(
        H, Wqkv, F, 0, q_bias + i*F, v_bias + i*F,
        nullptr, nullptr, Qb, Kb, Vt);
    attn_kernel<<<dim3(NB*NH, NPAD/64), 256, 0, stream>>>(Qb, Kb, Vt, Bias, Ob);
    gemm_kernel<1,1><<<dim3(MROWS/64, F/128, 2), 256, 0, stream>>>(
        Ob, Wproj, F, 0, proj_b + i*F, scale_attn + i*F,
        X, nullptr, nullptr, nullptr, nullptr);

    ln_kernel<<<NB*NTOK, 256, 0, stream>>>(X, ln2_g + i*F, ln2_b + i*F, H);
    gemm_kernel<2,2><<<dim3(MROWS/128, HID/128), 256, 0, stream>>>(
        H, Wm1, F, HID, mlp_b1 + i*HID, nullptr,
        nullptr, M1, nullptr, nullptr, nullptr);
    gemm_kernel<1,1><<<dim3(MROWS/64, F/128, 2), 256, 0, stream>>>(
        M1, Wm2, HID, 0, mlp_b2 + i*F, scale_mlp + i*F,
        X, nullptr, nullptr, nullptr, nullptr);
  }
}

// Round 3
// 2005.881 us; speedup vs baseline: 1.0636x; 1.0636x over previous
//
#include <hip/hip_runtime.h>
#include <cstdint>
#include <cstddef>

typedef __bf16 bf16;
typedef __bf16 bf16x8 __attribute__((ext_vector_type(8)));
typedef __bf16 bf16x4v __attribute__((ext_vector_type(4)));
typedef float f32x4 __attribute__((ext_vector_type(4)));
typedef unsigned int u32x4 __attribute__((ext_vector_type(4)));

static constexpr int NB = 8, NH = 16, F = 1024, FH = 64, NTOK = 577, NPAD = 640;
static constexpr int NLAYER = 6, HID = 4096, NRD = 2212;
static constexpr int MROWS = NB * NPAD; // 5120

// ---- workspace layout (bytes) ----
static constexpr size_t H_OFF    = 0;                                   // [5120][1024] bf16
static constexpr size_t Q_OFF    = H_OFF    + (size_t)MROWS*F*2;        // [8][16][640][64] bf16
static constexpr size_t K_OFF    = Q_OFF    + (size_t)NB*NH*NPAD*FH*2;
static constexpr size_t V_OFF    = K_OFF    + (size_t)NB*NH*NPAD*FH*2;  // [8][16][64][640] bf16 (transposed)
static constexpr size_t O_OFF    = V_OFF    + (size_t)NB*NH*FH*NPAD*2;  // [5120][1024] bf16
static constexpr size_t BIAS_OFF = O_OFF    + (size_t)MROWS*F*2;        // [16][640][640] f32
static constexpr size_t M1_OFF   = BIAS_OFF + (size_t)NH*NPAD*NPAD*4;   // [5120][4096] bf16
static constexpr size_t WQKV_OFF = M1_OFF   + (size_t)MROWS*HID*2;
static constexpr size_t WPROJ_OFF= WQKV_OFF + (size_t)3*F*F*2;
static constexpr size_t WM1_OFF  = WPROJ_OFF+ (size_t)F*F*2;
static constexpr size_t WM2_OFF  = WM1_OFF  + (size_t)HID*F*2;
static constexpr size_t WS_NEED  = WM2_OFF  + (size_t)HID*F*2;

__device__ __forceinline__ f32x4 mfma16(bf16x8 a, bf16x8 b, f32x4 c) {
  return __builtin_amdgcn_mfma_f32_16x16x32_bf16(a, b, c, 0, 0, 0);
}

// async global(16B per lane) -> LDS (wave-uniform base + lane*16)
__device__ __forceinline__ void gload16(const bf16* g, bf16* l) {
  __builtin_amdgcn_global_load_lds(
      (const __attribute__((address_space(1))) void*)g,
      (__attribute__((address_space(3))) void*)l, 16, 0, 0);
}

// ---------------- elementwise helpers ----------------
__global__ __launch_bounds__(256) void copy_kernel(const float* __restrict__ s, float* __restrict__ d) {
  size_t i = ((size_t)blockIdx.x*256 + threadIdx.x)*4;
  *(float4*)(d + i) = *(const float4*)(s + i);
}

// fused fp32->bf16 convert of the 4 weight matrices of one layer
static constexpr int CVT_N0 = 3*F*F;           // 3145728
static constexpr int CVT_N1 = CVT_N0 + F*F;    // 4194304
static constexpr int CVT_N2 = CVT_N1 + HID*F;  // 8388608
static constexpr int CVT_N3 = CVT_N2 + F*HID;  // 12582912
__global__ __launch_bounds__(256) void cvt4_kernel(
    const float* __restrict__ s0, const float* __restrict__ s1,
    const float* __restrict__ s2, const float* __restrict__ s3,
    bf16* __restrict__ d0, bf16* __restrict__ d1,
    bf16* __restrict__ d2, bf16* __restrict__ d3) {
  int i = (blockIdx.x*256 + threadIdx.x)*4;
  const float* s; bf16* d; int off;
  if (i < CVT_N0)      { s = s0; d = d0; off = i; }
  else if (i < CVT_N1) { s = s1; d = d1; off = i - CVT_N0; }
  else if (i < CVT_N2) { s = s2; d = d2; off = i - CVT_N1; }
  else                 { s = s3; d = d3; off = i - CVT_N2; }
  float4 v = *(const float4*)(s + off);
  bf16x4v o;
  o[0] = (bf16)v.x; o[1] = (bf16)v.y; o[2] = (bf16)v.z; o[3] = (bf16)v.w;
  *(bf16x4v*)(d + off) = o;
}

// LayerNorm: X (fp32, [B,577,1024]) -> H (bf16, padded rows [B,640,1024])
__global__ __launch_bounds__(256) void ln_kernel(const float* __restrict__ X,
    const float* __restrict__ g, const float* __restrict__ bta, bf16* __restrict__ H) {
  int row = blockIdx.x;                 // 0..4615  (b*577+tok)
  int bb = row / NTOK, tok = row % NTOK;
  const float* x = X + (size_t)row * F;
  int tid = threadIdx.x;
  float4 v = *(const float4*)(x + tid*4);
  float s  = v.x + v.y + v.z + v.w;
  float s2 = v.x*v.x + v.y*v.y + v.z*v.z + v.w*v.w;
  #pragma unroll
  for (int off = 1; off < 64; off <<= 1) {
    s  += __shfl_xor(s,  off, 64);
    s2 += __shfl_xor(s2, off, 64);
  }
  __shared__ float red[8];
  int w = tid >> 6;
  if ((tid & 63) == 0) { red[w] = s; red[4+w] = s2; }
  __syncthreads();
  s  = red[0]+red[1]+red[2]+red[3];
  s2 = red[4]+red[5]+red[6]+red[7];
  float mean = s * (1.0f/1024.0f);
  float var  = s2 * (1.0f/1024.0f) - mean*mean;
  float rstd = rsqrtf(fmaxf(var, 0.0f) + 1e-6f);
  float4 gg  = *(const float4*)(g + tid*4);
  float4 bb4 = *(const float4*)(bta + tid*4);
  bf16x4v o;
  o[0] = (bf16)((v.x-mean)*rstd*gg.x + bb4.x);
  o[1] = (bf16)((v.y-mean)*rstd*gg.y + bb4.y);
  o[2] = (bf16)((v.z-mean)*rstd*gg.z + bb4.z);
  o[3] = (bf16)((v.w-mean)*rstd*gg.w + bb4.w);
  *(bf16x4v*)(H + ((size_t)bb*NPAD + tok)*F + tid*4) = o;
}

// Relative-position bias plane: [16][640][640] fp32; pads = -1e30 (doubles as col mask)
__global__ __launch_bounds__(256) void bias_kernel(const float* __restrict__ table, float* __restrict__ bias) {
  int bi = blockIdx.x;           // 16*640
  int h = bi / NPAD, n = bi % NPAD;
  float* out = bias + ((size_t)h*NPAD + n)*NPAD;
  for (int m = threadIdx.x; m < NPAD; m += 256) {
    float val;
    if (n >= NTOK || m >= NTOK) val = -1e30f;
    else {
      int idx;
      if (n == 0 && m == 0) idx = NRD - 1;
      else if (m == 0)      idx = NRD - 2;
      else if (n == 0)      idx = NRD - 3;
      else {
        int pn = n - 1, pm = m - 1;
        int rn = pn / 24, cn = pn % 24, rm = pm / 24, cm = pm % 24;
        idx = (rn - rm + 23)*47 + (cn - cm + 23);
      }
      val = table[idx*NH + h];
    }
    out[m] = val;
  }
}

// ---------------- GEMM: C[m,n] = A[m,:] . Bw[n,:]  (both K-contiguous bf16) ----------------
// BMT: 1 -> BM=64 (grid-fill for small N), 2 -> BM=128.  BN=128, BK=32, 256 threads.
// Staging: global_load_lds dwordx4, double-buffered LDS, T3-minimum prefetch schedule:
//   stage(t=0); barrier; loop { stage(t+1, buf^1); ds_read+MFMA(buf); barrier; }
// The single barrier per K-step drains vmcnt AFTER the compute phase, so the next tile's
// loads fly under the current tile's MFMAs (vs. the serial stage->drain->compute structure
// whose stage+drain critical path is unhidden regardless of occupancy — R2 falsified TLP).
// EPI 0: qkv split->Q,K,Vt   EPI 1: x += p1[n]*(acc+p0[n]) (fp32)   EPI 2: gelu->bf16 bout
template<int BMT, int EPI>
__global__ __launch_bounds__(256, 2)
void gemm_kernel(const bf16* __restrict__ A, const bf16* __restrict__ Bw, int K, int ldc,
                 const float* __restrict__ p0, const float* __restrict__ p1,
                 float* __restrict__ xout, bf16* __restrict__ bout,
                 bf16* __restrict__ q_out, bf16* __restrict__ k_out, bf16* __restrict__ v_out)
{
  constexpr int BM = 64*BMT;
  constexpr int WN = (BMT==2) ? 2 : 4;      // waves along N
  constexpr int NF = 128/(WN*16);           // B frags per wave: 4 (BMT=2) or 2 (BMT=1)
  __shared__ bf16 As[2][BM*32], Bs[2][128*32];
  const int tid = threadIdx.x;
  const int lane = tid & 63, w = tid >> 6;
  const int wm = (BMT==2) ? (w>>1) : 0;
  const int wn = (BMT==2) ? (w&1) : w;
  const int lg = lane >> 4, lr = lane & 15;
  const int m0 = blockIdx.x * BM, n0 = blockIdx.y * 128;

  const f32x4 fz = {0.f, 0.f, 0.f, 0.f};
  f32x4 acc[4][NF];
  #pragma unroll
  for (int i = 0; i < 4; ++i)
    #pragma unroll
    for (int j = 0; j < NF; ++j) acc[i][j] = fz;

  // per-lane global source within a 16-row (1024B) load granule
  const int srow = lane >> 2;        // 0..15
  const int scol = (lane & 3) * 8;   // bf16 col

  auto stage = [&](int buf, int kt) {
    if (BMT == 2) {
      #pragma unroll
      for (int j = 0; j < 2; ++j) {
        int li = w + j*4;
        gload16(A + (size_t)(m0 + li*16 + srow)*K + kt + scol, &As[buf][li*512]);
      }
    } else {
      gload16(A + (size_t)(m0 + w*16 + srow)*K + kt + scol, &As[buf][w*512]);
    }
    #pragma unroll
    for (int j = 0; j < 2; ++j) {
      int li = w*2 + j;
      gload16(Bw + (size_t)(n0 + li*16 + srow)*K + kt + scol, &Bs[buf][li*512]);
    }
  };

  const int nk = K >> 5;             // K/32 steps
  stage(0, 0);
  __syncthreads();                   // tile 0 landed (implicit vmcnt(0))

  for (int t = 0; t < nk; ++t) {
    const int cur = t & 1;
    if (t + 1 < nk) stage(cur ^ 1, (t + 1) << 5);   // prefetch next tile first
    bf16x8 af[4], bfv[NF];
    #pragma unroll
    for (int f = 0; f < 4; ++f)
      af[f]  = *(const bf16x8*)&As[cur][(wm*64 + f*16 + lr)*32 + lg*8];
    #pragma unroll
    for (int f = 0; f < NF; ++f)
      bfv[f] = *(const bf16x8*)&Bs[cur][(wn*(NF*16) + f*16 + lr)*32 + lg*8];
    #pragma unroll
    for (int mf = 0; mf < 4; ++mf)
      #pragma unroll
      for (int nf = 0; nf < NF; ++nf)
        acc[mf][nf] = mfma16(af[mf], bfv[nf], acc[mf][nf]);
    __syncthreads();                 // drains prefetch loads; frees buf cur for t+1's stage
  }

  #pragma unroll
  for (int mf = 0; mf < 4; ++mf) {
    const int row = m0 + wm*64 + mf*16 + lg*4;       // + r (4-row group never crosses 640)
    const int bidx = row / NPAD;
    const int tokbase = row - bidx*NPAD;
    #pragma unroll
    for (int nf = 0; nf < NF; ++nf) {
      const int col = n0 + wn*(NF*16) + nf*16 + lr;
      if (EPI == 0) {
        const int sec = col >> 10, ci = col & 1023;
        const int hh = ci >> 6, fh = ci & 63;
        const size_t bhh = (size_t)bidx*NH + hh;
        #pragma unroll
        for (int r = 0; r < 4; ++r) {
          float v = acc[mf][nf][r];
          if (sec == 0)      q_out[(bhh*NPAD + tokbase + r)*FH + fh] = (bf16)((v + p0[ci]) * 0.125f);
          else if (sec == 1) k_out[(bhh*NPAD + tokbase + r)*FH + fh] = (bf16)v;
          else               v_out[(bhh*FH + fh)*NPAD + tokbase + r] = (bf16)(v + p1[ci]);
        }
      } else if (EPI == 1) {
        const float pb = p0[col], sc = p1[col];
        #pragma unroll
        for (int r = 0; r < 4; ++r) {
          int tok = tokbase + r;
          if (tok < NTOK) {
            size_t idx = ((size_t)bidx*NTOK + tok)*F + col;
            xout[idx] += sc * (acc[mf][nf][r] + pb);
          }
        }
      } else {
        const float pb = p0[col];
        #pragma unroll
        for (int r = 0; r < 4; ++r) {
          float t = acc[mf][nf][r] + pb;
          float gl = 0.5f*t*(1.0f + erff(t*0.70710678118f));
          bout[(size_t)(row + r)*ldc + col] = (bf16)gl;
        }
      }
    }
  }
}

// ---------------- flash attention: Q[B,H,640,64], K[B,H,640,64], Vt[B,H,64,640] -> O[5120][1024] bf16
__global__ __launch_bounds__(256, 2) void attn_kernel(
    const bf16* __restrict__ Qb, const bf16* __restrict__ Kb,
    const bf16* __restrict__ Vt, const float* __restrict__ Bias,
    bf16* __restrict__ O)
{
  __shared__ bf16 Qt[64*72], Kt[64*72], Vs[64*72], Pt[4][16*72];
  const int bh = blockIdx.x, rb = blockIdx.y;
  const int b = bh >> 4, h = bh & 15;
  const int tid = threadIdx.x, lane = tid & 63, w = tid >> 6;
  const int lg = lane >> 4, lr = lane & 15;

  const bf16*  Qg = Qb + ((size_t)bh*NPAD + rb*64)*FH;
  const bf16*  Kg = Kb + (size_t)bh*NPAD*FH;
  const bf16*  Vg = Vt + (size_t)bh*FH*NPAD;
  const float* Bg = Bias + (size_t)h*NPAD*NPAD;

  #pragma unroll
  for (int i = 0; i < 2; ++i) {
    int gidx = tid + i*256, r = gidx >> 3, cg = gidx & 7;
    *(u32x4*)&Qt[r*72 + cg*8] = *(const u32x4*)&Qg[r*64 + cg*8];
  }
  __syncthreads();
  bf16x8 qf0 = *(const bf16x8*)&Qt[(w*16+lr)*72 + lg*8];
  bf16x8 qf1 = *(const bf16x8*)&Qt[(w*16+lr)*72 + 32 + lg*8];

  const f32x4 fz = {0.f, 0.f, 0.f, 0.f};
  float m_run[4], l_run[4];
  f32x4 o_acc[4];
  #pragma unroll
  for (int r = 0; r < 4; ++r) { m_run[r] = -3.0e38f; l_run[r] = 0.0f; }
  #pragma unroll
  for (int f = 0; f < 4; ++f) o_acc[f] = fz;

  const int qrow = rb*64 + w*16 + lg*4;

  for (int cb = 0; cb < 10; ++cb) {
    __syncthreads();
    #pragma unroll
    for (int i = 0; i < 2; ++i) {
      int gidx = tid + i*256, r = gidx >> 3, cg = gidx & 7;
      *(u32x4*)&Kt[r*72 + cg*8] = *(const u32x4*)&Kg[(size_t)(cb*64+r)*64 + cg*8];
      *(u32x4*)&Vs[r*72 + cg*8] = *(const u32x4*)&Vg[(size_t)r*NPAD + cb*64 + cg*8];
    }
    __syncthreads();

    f32x4 s[4];
    #pragma unroll
    for (int nf = 0; nf < 4; ++nf) {
      bf16x8 k0 = *(const bf16x8*)&Kt[(nf*16+lr)*72 + lg*8];
      bf16x8 k1 = *(const bf16x8*)&Kt[(nf*16+lr)*72 + 32 + lg*8];
      s[nf] = mfma16(qf1, k1, mfma16(qf0, k0, fz));
    }
    #pragma unroll
    for (int nf = 0; nf < 4; ++nf)
      #pragma unroll
      for (int r = 0; r < 4; ++r)
        s[nf][r] += Bg[(size_t)(qrow + r)*NPAD + cb*64 + nf*16 + lr];

    float pm[4], sc[4], rs[4];
    #pragma unroll
    for (int r = 0; r < 4; ++r)
      pm[r] = fmaxf(fmaxf(s[0][r], s[1][r]), fmaxf(s[2][r], s[3][r]));
    #pragma unroll
    for (int off = 1; off < 16; off <<= 1)
      #pragma unroll
      for (int r = 0; r < 4; ++r)
        pm[r] = fmaxf(pm[r], __shfl_xor(pm[r], off, 64));
    #pragma unroll
    for (int r = 0; r < 4; ++r) {
      float mn = fmaxf(m_run[r], pm[r]);
      sc[r] = __expf(m_run[r] - mn);
      m_run[r] = mn;
      rs[r] = 0.0f;
    }
    #pragma unroll
    for (int nf = 0; nf < 4; ++nf)
      #pragma unroll
      for (int r = 0; r < 4; ++r) {
        float p = __expf(s[nf][r] - m_run[r]);
        s[nf][r] = p;
        rs[r] += p;
      }
    #pragma unroll
    for (int off = 1; off < 16; off <<= 1)
      #pragma unroll
      for (int r = 0; r < 4; ++r)
        rs[r] += __shfl_xor(rs[r], off, 64);
    #pragma unroll
    for (int r = 0; r < 4; ++r) l_run[r] = l_run[r]*sc[r] + rs[r];
    #pragma unroll
    for (int f = 0; f < 4; ++f) {
      o_acc[f][0] *= sc[0]; o_acc[f][1] *= sc[1];
      o_acc[f][2] *= sc[2]; o_acc[f][3] *= sc[3];
    }
    bf16* Ptw = &Pt[w][0];
    #pragma unroll
    for (int nf = 0; nf < 4; ++nf)
      #pragma unroll
      for (int r = 0; r < 4; ++r)
        Ptw[(lg*4 + r)*72 + nf*16 + lr] = (bf16)s[nf][r];
    __syncthreads();
    #pragma unroll
    for (int kc = 0; kc < 2; ++kc) {
      bf16x8 pa = *(const bf16x8*)&Ptw[lr*72 + kc*32 + lg*8];
      #pragma unroll
      for (int f = 0; f < 4; ++f) {
        bf16x8 vf = *(const bf16x8*)&Vs[(f*16+lr)*72 + kc*32 + lg*8];
        o_acc[f] = mfma16(pa, vf, o_acc[f]);
      }
    }
  }

  const int tokr = rb*64 + w*16 + lg*4;
  #pragma unroll
  for (int f = 0; f < 4; ++f)
    #pragma unroll
    for (int r = 0; r < 4; ++r) {
      float ov = o_acc[f][r] / l_run[r];
      O[((size_t)b*NPAD + tokr + r)*F + h*64 + f*16 + lr] = (bf16)ov;
    }
}

extern "C" void kernel_launch(void* const* d_in, const int* in_sizes, int n_in,
                              void* d_out, int out_size, void* d_ws, size_t ws_size,
                              hipStream_t stream) {
  (void)in_sizes; (void)n_in; (void)out_size;
  if (ws_size < WS_NEED) return;

  const float* tokens     = (const float*)d_in[0];
  const float* ln1_g      = (const float*)d_in[1];
  const float* ln1_b      = (const float*)d_in[2];
  const float* q_bias     = (const float*)d_in[3];
  const float* v_bias     = (const float*)d_in[4];
  const float* qkv_w      = (const float*)d_in[5];
  const float* relpos     = (const float*)d_in[6];
  const float* proj_w     = (const float*)d_in[7];
  const float* proj_b     = (const float*)d_in[8];
  const float* scale_attn = (const float*)d_in[9];
  const float* ln2_g      = (const float*)d_in[10];
  const float* ln2_b      = (const float*)d_in[11];
  const float* mlp_w1     = (const float*)d_in[12];
  const float* mlp_b1     = (const float*)d_in[13];
  const float* mlp_w2     = (const float*)d_in[14];
  const float* mlp_b2     = (const float*)d_in[15];
  const float* scale_mlp  = (const float*)d_in[16];

  char* ws = (char*)d_ws;
  bf16*  H     = (bf16*)(ws + H_OFF);
  bf16*  Qb    = (bf16*)(ws + Q_OFF);
  bf16*  Kb    = (bf16*)(ws + K_OFF);
  bf16*  Vt    = (bf16*)(ws + V_OFF);
  bf16*  Ob    = (bf16*)(ws + O_OFF);
  float* Bias  = (float*)(ws + BIAS_OFF);
  bf16*  M1    = (bf16*)(ws + M1_OFF);
  bf16*  Wqkv  = (bf16*)(ws + WQKV_OFF);
  bf16*  Wproj = (bf16*)(ws + WPROJ_OFF);
  bf16*  Wm1   = (bf16*)(ws + WM1_OFF);
  bf16*  Wm2   = (bf16*)(ws + WM2_OFF);
  float* X     = (float*)d_out;

  copy_kernel<<<NB*NTOK, 256, 0, stream>>>(tokens, X);   // x = tokens (fp32 residual stream)

  for (int i = 0; i < NLAYER; ++i) {
    cvt4_kernel<<<CVT_N3/(256*4), 256, 0, stream>>>(
        qkv_w + (size_t)i*3*F*F, proj_w + (size_t)i*F*F,
        mlp_w1 + (size_t)i*HID*F, mlp_w2 + (size_t)i*F*HID,
        Wqkv, Wproj, Wm1, Wm2);
    bias_kernel<<<NH*NPAD, 256, 0, stream>>>(relpos + (size_t)i*NRD*NH, Bias);

    ln_kernel<<<NB*NTOK, 256, 0, stream>>>(X, ln1_g + i*F, ln1_b + i*F, H);
    gemm_kernel<2,0><<<dim3(MROWS/128, 3*F/128), 256, 0, stream>>>(
        H, Wqkv, F, 0, q_bias + i*F, v_bias + i*F,
        nullptr, nullptr, Qb, Kb, Vt);
    attn_kernel<<<dim3(NB*NH, NPAD/64), 256, 0, stream>>>(Qb, Kb, Vt, Bias, Ob);
    gemm_kernel<1,1><<<dim3(MROWS/64, F/128), 256, 0, stream>>>(
        Ob, Wproj, F, 0, proj_b + i*F, scale_attn + i*F,
        X, nullptr, nullptr, nullptr, nullptr);

    ln_kernel<<<NB*NTOK, 256, 0, stream>>>(X, ln2_g + i*F, ln2_b + i*F, H);
    gemm_kernel<2,2><<<dim3(MROWS/128, HID/128), 256, 0, stream>>>(
        H, Wm1, F, HID, mlp_b1 + i*HID, nullptr,
        nullptr, M1, nullptr, nullptr, nullptr);
    gemm_kernel<1,1><<<dim3(MROWS/64, F/128), 256, 0, stream>>>(
        M1, Wm2, HID, 0, mlp_b2 + i*F, scale_mlp + i*F,
        X, nullptr, nullptr, nullptr, nullptr);
  }
}